// Round 1
// baseline (450.569 us; speedup 1.0000x reference)
//
#include <hip/hip_runtime.h>
#include <math.h>

// Problem dims (fixed by the reference)
#define BN    32          // batch
#define TN    512         // TFs
#define GN    2000        // genes
#define PPGN  10          // peaks per gene
#define PN    (GN*PPGN)   // 20000 peaks
#define EN    64000       // edges
#define NOUTN 10          // output channels
#define BGN   8           // batches per thread in k_perpeak

// Stage 1: per_peak[b,p] = sum_t x[b,t,p] * W_sub[t,p]
// Lanes take consecutive p -> coalesced 256B wave loads; each thread handles
// BGN batches for ILP and to amortize the W_sub read (W_sub re-read B/BGN=4x,
// L3-resident at 41MB).
__global__ void k_perpeak(const float* __restrict__ x,
                          const float* __restrict__ W_sub,
                          float* __restrict__ per_peak) {
    int idx = blockIdx.x * blockDim.x + threadIdx.x;
    if (idx >= (BN / BGN) * PN) return;
    int p  = idx % PN;
    int bg = idx / PN;

    float acc[BGN];
#pragma unroll
    for (int j = 0; j < BGN; ++j) acc[j] = 0.0f;

    const float* xp = x + (size_t)bg * BGN * TN * PN + p;
    const float* wp = W_sub + p;

    for (int t = 0; t < TN; ++t) {
        float w = wp[(size_t)t * PN];
#pragma unroll
        for (int j = 0; j < BGN; ++j)
            acc[j] = fmaf(xp[(size_t)j * TN * PN + (size_t)t * PN], w, acc[j]);
    }
#pragma unroll
    for (int j = 0; j < BGN; ++j)
        per_peak[(size_t)(bg * BGN + j) * PN + p] = acc[j];
}

// Stage 2: h[b,g] = relu(sum_{k<10} per_peak[b, g*10+k] + b_sub[g])
__global__ void k_h(const float* __restrict__ per_peak,
                    const float* __restrict__ b_sub,
                    float* __restrict__ h) {
    int idx = blockIdx.x * blockDim.x + threadIdx.x;
    if (idx >= BN * GN) return;
    int g = idx % GN, b = idx / GN;
    const float* pp = per_peak + (size_t)b * PN + g * PPGN;
    float s = b_sub[g];
#pragma unroll
    for (int k = 0; k < PPGN; ++k) s += pp[k];
    h[idx] = fmaxf(s, 0.0f);
}

// Stage 3a: degree of target nodes (col)
__global__ void k_deg(const int* __restrict__ col, float* __restrict__ deg) {
    int e = blockIdx.x * blockDim.x + threadIdx.x;
    if (e < EN) atomicAdd(&deg[col[e]], 1.0f);
}

// Stage 3b: dinv = deg^-1/2 (0 where deg == 0)
__global__ void k_dinv(const float* __restrict__ deg, float* __restrict__ dinv) {
    int g = blockIdx.x * blockDim.x + threadIdx.x;
    if (g < GN) {
        float d = deg[g];
        dinv[g] = (d > 0.0f) ? (1.0f / sqrtf(d)) : 0.0f;
    }
}

// Stage 3c: s[b,g] = sum_{e: col[e]==g} dinv[row]*dinv[col] * h[b,row]
// (GCNConv is rank-1 in the channel dim: agg[b,g,c] = W_gcn[c]*s[b,g] + b_gcn[c])
__global__ void k_s(const int* __restrict__ row, const int* __restrict__ col,
                    const float* __restrict__ dinv, const float* __restrict__ h,
                    float* __restrict__ s) {
    int idx = blockIdx.x * blockDim.x + threadIdx.x;
    if (idx >= EN * BN) return;
    int b = idx % BN;      // lanes 0..31 share e -> broadcast row/col loads
    int e = idx / BN;
    int r = row[e], c = col[e];
    float nrm = dinv[r] * dinv[c];
    atomicAdd(&s[(size_t)b * GN + c], nrm * h[(size_t)b * GN + r]);
}

// Stage 4: out[b,n] = sum_g sum_c relu(W_gcn[c]*s[b,g]+b_gcn[c]) * W_out[n, 2g+c] + b_out[n]
// One wave (64 threads) per (b,n).
__global__ void k_out(const float* __restrict__ s,
                      const float* __restrict__ W_gcn,
                      const float* __restrict__ b_gcn,
                      const float* __restrict__ W_out,
                      const float* __restrict__ b_out,
                      float* __restrict__ out) {
    int b = blockIdx.x / NOUTN;
    int n = blockIdx.x % NOUTN;
    int lane = threadIdx.x;

    float w0 = W_gcn[0], w1 = W_gcn[1];
    float c0 = b_gcn[0], c1 = b_gcn[1];

    float acc = 0.0f;
    for (int g = lane; g < GN; g += 64) {
        float sv = s[(size_t)b * GN + g];
        float g0 = fmaxf(fmaf(sv, w0, c0), 0.0f);
        float g1 = fmaxf(fmaf(sv, w1, c1), 0.0f);
        const float* wo = &W_out[(size_t)n * (GN * 2) + 2 * g];
        acc = fmaf(g0, wo[0], acc);
        acc = fmaf(g1, wo[1], acc);
    }
#pragma unroll
    for (int off = 32; off > 0; off >>= 1)
        acc += __shfl_down(acc, off);
    if (lane == 0) out[b * NOUTN + n] = acc + b_out[n];
}

extern "C" void kernel_launch(void* const* d_in, const int* in_sizes, int n_in,
                              void* d_out, int out_size, void* d_ws, size_t ws_size,
                              hipStream_t stream) {
    const float* x         = (const float*)d_in[0];
    const int*   edge_index= (const int*)  d_in[1];
    const float* W_sub     = (const float*)d_in[2];
    const float* b_sub     = (const float*)d_in[3];
    const float* W_gcn     = (const float*)d_in[4];
    const float* b_gcn     = (const float*)d_in[5];
    const float* W_out     = (const float*)d_in[6];
    const float* b_out     = (const float*)d_in[7];
    float* out = (float*)d_out;

    char* ws = (char*)d_ws;
    float* per_peak = (float*)(ws);                 // B*P   floats = 2,560,000 B
    float* h        = (float*)(ws + 2560000);       // B*G   floats =   256,000 B
    float* deg      = (float*)(ws + 2816000);       // G     floats =     8,000 B
    float* dinv     = (float*)(ws + 2824000);       // G     floats =     8,000 B
    float* s        = (float*)(ws + 2832000);       // B*G   floats =   256,000 B

    const int* row = edge_index;        // edge_index[0,:]
    const int* col = edge_index + EN;   // edge_index[1,:]

    // zero the atomic-accumulated buffers every call (graph-capture legal)
    hipMemsetAsync(deg, 0, GN * sizeof(float), stream);
    hipMemsetAsync(s,   0, (size_t)BN * GN * sizeof(float), stream);

    k_perpeak<<<(((BN / BGN) * PN) + 255) / 256, 256, 0, stream>>>(x, W_sub, per_peak);
    k_h      <<<((BN * GN) + 255) / 256,       256, 0, stream>>>(per_peak, b_sub, h);
    k_deg    <<<(EN + 255) / 256,              256, 0, stream>>>(col, deg);
    k_dinv   <<<(GN + 255) / 256,              256, 0, stream>>>(deg, dinv);
    k_s      <<<((EN * BN) + 255) / 256,       256, 0, stream>>>(row, col, dinv, h, s);
    k_out    <<<BN * NOUTN, 64, 0, stream>>>(s, W_gcn, b_gcn, W_out, b_out, out);
}